// Round 4
// baseline (248.420 us; speedup 1.0000x reference)
//
#include <hip/hip_runtime.h>

// GrCNet attention layer — CSR gather formulation.
//   u[n] = W1 x[n], v[n] = W2 x[n]   (a = [W1 | W2], [64,128] row-major)
//   su[n] = u[n].a2, sv[n] = v[n].a2
//   edge e: g = 0.5*(G[s,t]+G[d,t]); ee = exp(-lrelu(g*(su[s]+sv[d]))); w = ee*g
//   rowsum[s] += ee (atomic, in edge_place); CSR stores packed (d, w)
//   h[n] = elu( ((Σw)·u[n] + Σ w·v[d]) / rowsum[n] )
//
// Round 4: fused 3-kernel scan -> 1 chained-lookback scan; csr_ee dropped
// (rowsum atomics in place); csr packed int2; aggregate j-loop unrolled x4.

#define LRELU_ALPHA 0.2f
#define SCAN_BLOCK 256
#define SCAN_ITEMS 8
#define SCAN_TILE (SCAN_BLOCK * SCAN_ITEMS)  // 2048

__global__ __launch_bounds__(256) void node_transform_kernel(
    const float* __restrict__ x, const float* __restrict__ a,
    const float* __restrict__ a2,
    float* __restrict__ u, float* __restrict__ v,
    float* __restrict__ su, float* __restrict__ sv,
    int* __restrict__ count, float* __restrict__ rowsum,
    int* __restrict__ tileflag, int nflags, int N)
{
    __shared__ float a_lds[64][129];
    for (int idx = threadIdx.x; idx < 64 * 128; idx += 256)
        a_lds[idx >> 7][idx & 127] = a[idx];
    if (blockIdx.x == 0) {
        for (int i = threadIdx.x; i < nflags; i += 256) tileflag[i] = 0;
    }
    __syncthreads();

    const int wave = threadIdx.x >> 6;
    const int lane = threadIdx.x & 63;
    const int n = blockIdx.x * 4 + wave;
    if (n >= N) return;

    if (lane == 0) { count[n] = 0; rowsum[n] = 0.f; }

    const float a2v = a2[lane];
    const float* xr = x + (size_t)n * 64;
    float uo = 0.f, vo = 0.f;
#pragma unroll 8
    for (int i = 0; i < 64; ++i) {
        const float xi = xr[i];
        uo += xi * a_lds[lane][i];
        vo += xi * a_lds[lane][64 + i];
    }
    u[(size_t)n * 64 + lane] = uo;
    v[(size_t)n * 64 + lane] = vo;

    float sup = uo * a2v, svp = vo * a2v;
#pragma unroll
    for (int m = 1; m < 64; m <<= 1) {
        sup += __shfl_xor(sup, m, 64);
        svp += __shfl_xor(svp, m, 64);
    }
    if (lane == 0) { su[n] = sup; sv[n] = svp; }
}

__global__ __launch_bounds__(256) void hist_kernel(
    const int* __restrict__ edge, int* __restrict__ count, int E)
{
    const int i = blockIdx.x * 256 + threadIdx.x;
    if (i < E) atomicAdd(&count[edge[i]], 1);
}

// single-kernel exclusive scan (chained lookback; nsb=25 blocks, all co-resident)
__global__ __launch_bounds__(SCAN_BLOCK) void scan_fused_kernel(
    const int* __restrict__ count, int* __restrict__ base,
    int* __restrict__ cursor,
    int* __restrict__ tilesum, int* __restrict__ tileflag, int N)
{
    __shared__ int lds[SCAN_BLOCK];
    __shared__ int s_prefix;
    const int b = blockIdx.x, t = threadIdx.x;
    const int idx0 = b * SCAN_TILE + t * SCAN_ITEMS;
    int vals[SCAN_ITEMS];
    int s = 0;
#pragma unroll
    for (int k = 0; k < SCAN_ITEMS; ++k) {
        const int idx = idx0 + k;
        const int c = (idx < N) ? count[idx] : 0;
        vals[k] = s; s += c;
    }
    lds[t] = s;
    __syncthreads();
    for (int off = 1; off < SCAN_BLOCK; off <<= 1) {
        const int xv = (t >= off) ? lds[t - off] : 0;
        __syncthreads();
        lds[t] += xv;
        __syncthreads();
    }
    if (t == 0) {
        const int total = lds[SCAN_BLOCK - 1];
        int prefix = 0;
        if (b > 0) {
            while (atomicAdd(&tileflag[b - 1], 0) == 0) {}
            prefix = atomicAdd(&tilesum[b - 1], 0);
        }
        atomicExch(&tilesum[b], prefix + total);
        __threadfence();
        atomicExch(&tileflag[b], 1);
        s_prefix = prefix;
    }
    __syncthreads();
    const int pfx = s_prefix;
    const int excl = (t == 0) ? 0 : lds[t - 1];
#pragma unroll
    for (int k = 0; k < SCAN_ITEMS; ++k) {
        const int idx = idx0 + k;
        if (idx < N) {
            const int bv = pfx + excl + vals[k];
            base[idx] = bv;
            cursor[idx] = bv;
        }
    }
}

// one THREAD per edge: scalar score, rowsum atomic, packed CSR placement
__global__ __launch_bounds__(256) void edge_place_kernel(
    const int* __restrict__ edge, const int* __restrict__ etype,
    const float* __restrict__ G, int R,
    const float* __restrict__ su, const float* __restrict__ sv,
    int* __restrict__ cursor, float* __restrict__ rowsum,
    int2* __restrict__ csr_dw, int E, int N)
{
    const int e = blockIdx.x * 256 + threadIdx.x;
    if (e >= E) return;
    const int s = edge[e];
    const int d = edge[(size_t)E + e];
    const int t = etype[e];
    if ((unsigned)s >= (unsigned)N || (unsigned)d >= (unsigned)N) return;

    const float g   = 0.5f * (G[s * R + t] + G[d * R + t]);
    const float raw = g * (su[s] + sv[d]);
    const float lr  = raw > 0.f ? raw : LRELU_ALPHA * raw;
    const float ee  = __expf(-lr);

    atomicAdd(&rowsum[s], ee);
    const int pos = atomicAdd(&cursor[s], 1);
    csr_dw[pos] = make_int2(d, __float_as_int(ee * g));
}

// one WAVE per node: register accumulation, x4-unrolled gather, fused finalize
__global__ __launch_bounds__(256) void aggregate_kernel(
    const int* __restrict__ base, const int2* __restrict__ csr_dw,
    const float* __restrict__ rowsum,
    const float* __restrict__ u, const float* __restrict__ v,
    float* __restrict__ out, int N, int E)
{
    const int wave = threadIdx.x >> 6;
    const int lane = threadIdx.x & 63;
    const int n = blockIdx.x * 4 + wave;
    if (n >= N) return;

    const int rs = base[n];
    const int re = (n + 1 < N) ? base[n + 1] : E;

    float val = 0.f, sumw_p = 0.f;

    for (int i = rs; i < re; i += 64) {
        const int m = min(64, re - i);
        int dl = 0; float wl = 0.f;
        if (lane < m) {
            const int2 p = csr_dw[i + lane];
            dl = p.x;
            wl = __int_as_float(p.y);
        }
        sumw_p += wl;
        int j = 0;
        for (; j + 4 <= m; j += 4) {
            const int   d0 = __shfl(dl, j,     64);
            const int   d1 = __shfl(dl, j + 1, 64);
            const int   d2 = __shfl(dl, j + 2, 64);
            const int   d3 = __shfl(dl, j + 3, 64);
            const float w0 = __shfl(wl, j,     64);
            const float w1 = __shfl(wl, j + 1, 64);
            const float w2 = __shfl(wl, j + 2, 64);
            const float w3 = __shfl(wl, j + 3, 64);
            const float v0 = v[d0 * 64 + lane];
            const float v1 = v[d1 * 64 + lane];
            const float v2 = v[d2 * 64 + lane];
            const float v3 = v[d3 * 64 + lane];
            val += w0 * v0;
            val += w1 * v1;
            val += w2 * v2;
            val += w3 * v3;
        }
        for (; j < m; ++j) {
            const int   dj = __shfl(dl, j, 64);
            const float wj = __shfl(wl, j, 64);
            val += wj * v[dj * 64 + lane];
        }
    }

    float sumw = sumw_p;
#pragma unroll
    for (int m2 = 1; m2 < 64; m2 <<= 1)
        sumw += __shfl_xor(sumw, m2, 64);

    val += sumw * u[n * 64 + lane];
    float r = rowsum[n];
    r = (r == 0.f) ? 1e-12f : r;
    const float h = val / r;
    out[n * 64 + lane] = (h > 0.f) ? h : expm1f(h);
}

extern "C" void kernel_launch(void* const* d_in, const int* in_sizes, int n_in,
                              void* d_out, int out_size, void* d_ws, size_t ws_size,
                              hipStream_t stream)
{
    const float* x     = (const float*)d_in[0];
    const int*   edge  = (const int*)d_in[1];
    // d_in[2] = edge_embed: unused by the reference computation
    const int*   etype = (const int*)d_in[3];
    const float* G     = (const float*)d_in[4];
    const float* a     = (const float*)d_in[5];
    const float* a2    = (const float*)d_in[6];

    const int N = in_sizes[0] / 64;
    const int E = in_sizes[1] / 2;
    const int R = in_sizes[4] / N;

    float* out = (float*)d_out;

    // workspace layout (~33 MB):
    // u[N*64] | v[N*64] | su[N] | sv[N] | rowsum[N] | count[N] | base[N] |
    // cursor[N] | tilesum[nsb] | tileflag[nsb] | csr_dw[E] (int2)
    float* u      = (float*)d_ws;
    float* v      = u + (size_t)N * 64;
    float* su     = v + (size_t)N * 64;
    float* sv     = su + N;
    float* rowsum = sv + N;
    int*   count  = (int*)(rowsum + N);
    int*   base   = count + N;
    int*   cursor = base + N;
    const int nsb = (N + SCAN_TILE - 1) / SCAN_TILE;
    int*   tilesum  = cursor + N;
    int*   tileflag = tilesum + ((nsb + 63) & ~63);
    int2*  csr_dw   = (int2*)(tileflag + ((nsb + 63) & ~63));

    node_transform_kernel<<<dim3((N + 3) / 4), dim3(256), 0, stream>>>(
        x, a, a2, u, v, su, sv, count, rowsum, tileflag, nsb, N);
    hist_kernel<<<dim3((E + 255) / 256), dim3(256), 0, stream>>>(edge, count, E);
    scan_fused_kernel<<<dim3(nsb), dim3(SCAN_BLOCK), 0, stream>>>(
        count, base, cursor, tilesum, tileflag, N);
    edge_place_kernel<<<dim3((E + 255) / 256), dim3(256), 0, stream>>>(
        edge, etype, G, R, su, sv, cursor, rowsum, csr_dw, E, N);
    aggregate_kernel<<<dim3((N + 3) / 4), dim3(256), 0, stream>>>(
        base, csr_dw, rowsum, u, v, out, N, E);
}